// Round 8
// baseline (266.929 us; speedup 1.0000x reference)
//
#include <hip/hip_runtime.h>
#include <hip/hip_bf16.h>

// Problem constants
constexpr int B = 8, N = 2048, J = 4, F = 16, C = 2;
constexpr int MCH = 16;              // m-chunks per group (reduction split)
constexpr int MR  = N / MCH;         // 128 m-rows per chunk (1 MB sequential W read)
constexpr int NH  = 4;               // n-quarters
constexpr int HN  = N / NH;          // 512 n per quarter
constexpr int NGROUP = B * NH;       // 32 groups
constexpr int GRID = NGROUP * MCH;   // 512 blocks

typedef float fx4 __attribute__((ext_vector_type(4)));

// ---- single main kernel: t-prep + W stream + last-arrival group reduce ----
__global__ __launch_bounds__(512) void gnn_main_kernel(
    const float* __restrict__ W,    // [B,N,N,J]
    const float* __restrict__ x,    // [B,F,N]
    const float* __restrict__ cw,   // [C, J*F]
    const float* __restrict__ cb,   // [C]
    float* __restrict__ part,       // [NGROUP][MCH][C][HN]
    int* __restrict__ ctr,          // [NGROUP], zeroed by memset each launch
    float* __restrict__ out)        // [B,N,C]
{
    __shared__ float s_cw[C * J * F];   // 128 floats
    __shared__ float tl[MR * 8];        // 4 KB: [m_local][c*4+j]
    __shared__ int isLast;

    const int tid = threadIdx.x;
    const int blk = blockIdx.x;          // g*MCH + mc
    const int g  = blk >> 4;
    const int mc = blk & (MCH - 1);
    const int b  = g >> 2;
    const int nh = g & (NH - 1);
    const int m0 = mc * MR;
    const int n0 = nh * HN;

    if (tid < C * J * F) s_cw[tid] = cw[tid];
    __syncthreads();

    // prologue: t[ml][c*4+j] = sum_f cw[c,j*F+f] * x[b,f,m0+ml]
    if (tid < MR) {   // 128 threads, coalesced x loads over m
        const float* xb = x + (size_t)b * F * N + m0 + tid;
        float xv[F];
#pragma unroll
        for (int f = 0; f < F; ++f) xv[f] = xb[(size_t)f * N];
#pragma unroll
        for (int c = 0; c < C; ++c) {
#pragma unroll
            for (int j = 0; j < J; ++j) {
                float s = 0.f;
#pragma unroll
                for (int f = 0; f < F; ++f) s += s_cw[c * (J * F) + j * F + f] * xv[f];
                tl[tid * 8 + c * 4 + j] = s;
            }
        }
    }
    __syncthreads();

    // main stream: W rows m0..m0+MR-1, n-range [n0, n0+HN)
    const fx4* Wp = (const fx4*)W + ((size_t)b * N + m0) * N + n0;  // one fx4 == one n

    float acc0 = 0.f, acc1 = 0.f;
#pragma unroll 4
    for (int r = 0; r < MR; ++r) {
        const float4 t0 = *(const float4*)&tl[r * 8];      // uniform LDS broadcast
        const float4 t1 = *(const float4*)&tl[r * 8 + 4];
        fx4 w4 = __builtin_nontemporal_load(Wp + (size_t)r * N + tid);  // wave: 1 KB contiguous
        acc0 += w4.x * t0.x + w4.y * t0.y + w4.z * t0.z + w4.w * t0.w;
        acc1 += w4.x * t1.x + w4.y * t1.y + w4.z * t1.z + w4.w * t1.w;
    }

    float* pb = part + ((size_t)(g * MCH + mc) * C) * HN;
    pb[tid]      = acc0;   // coalesced
    pb[HN + tid] = acc1;

    // ---- last-arrival reduce for this group ----
    __threadfence();       // each thread: make its partial stores device-visible
    __syncthreads();
    if (tid == 0) {
        int old = __hip_atomic_fetch_add(&ctr[g], 1, __ATOMIC_ACQ_REL,
                                         __HIP_MEMORY_SCOPE_AGENT);
        isLast = (old == MCH - 1);
    }
    __syncthreads();

    if (isLast) {
        __threadfence();   // acquire: see other blocks' partials
        const float* pg = part + (size_t)g * MCH * C * HN;
        float s0 = cb[0], s1 = cb[1];
#pragma unroll 8
        for (int m = 0; m < MCH; ++m) {
            s0 += pg[(size_t)(m * C + 0) * HN + tid];   // coalesced
            s1 += pg[(size_t)(m * C + 1) * HN + tid];
        }
        float2 ov; ov.x = s0; ov.y = s1;
        *(float2*)&out[(size_t)(b * N + n0 + tid) * C] = ov;
    }
}

extern "C" void kernel_launch(void* const* d_in, const int* in_sizes, int n_in,
                              void* d_out, int out_size, void* d_ws, size_t ws_size,
                              hipStream_t stream) {
    const float* W  = (const float*)d_in[0];
    const float* x  = (const float*)d_in[1];
    const float* cw = (const float*)d_in[2];
    const float* cb = (const float*)d_in[3];
    float* out  = (float*)d_out;
    float* part = (float*)d_ws;                        // NGROUP*MCH*C*HN floats = 2 MB
    int*   ctr  = (int*)(part + (size_t)NGROUP * MCH * C * HN);

    hipMemsetAsync(ctr, 0, NGROUP * sizeof(int), stream);   // graph-safe tiny fill
    gnn_main_kernel<<<dim3(GRID), dim3(512), 0, stream>>>(W, x, cw, cb, part, ctr, out);
}

// Round 9
// 89.459 us; speedup vs baseline: 2.9838x; 2.9838x over previous
//
#include <hip/hip_runtime.h>
#include <hip/hip_bf16.h>

// Problem constants
constexpr int B = 8, N = 2048, J = 4, F = 16, C = 2;
constexpr int MCH = 16;              // m-chunks per group (reduction split)
constexpr int MR  = N / MCH;         // 128 m-rows per chunk (1 MB sequential W read)
constexpr int NH  = 4;               // n-quarters
constexpr int HN  = N / NH;          // 512 n per quarter
constexpr int GRID = B * NH * MCH;   // 512 blocks

typedef float fx4 __attribute__((ext_vector_type(4)));

// ---- single main kernel: t-prep + W stream + atomic accumulate to out ----
__global__ __launch_bounds__(512) void gnn_main_kernel(
    const float* __restrict__ W,    // [B,N,N,J]
    const float* __restrict__ x,    // [B,F,N]
    const float* __restrict__ cw,   // [C, J*F]
    const float* __restrict__ cb,   // [C]
    float* __restrict__ out)        // [B,N,C], pre-zeroed each launch
{
    __shared__ float s_cw[C * J * F];   // 128 floats
    __shared__ float tl[MR * 8];        // 4 KB: [m_local][c*4+j]

    const int tid = threadIdx.x;
    const int blk = blockIdx.x;          // g*MCH + mc
    const int g  = blk >> 4;
    const int mc = blk & (MCH - 1);
    const int b  = g >> 2;
    const int nh = g & (NH - 1);
    const int m0 = mc * MR;
    const int n0 = nh * HN;

    if (tid < C * J * F) s_cw[tid] = cw[tid];
    __syncthreads();

    // prologue: t[ml][c*4+j] = sum_f cw[c,j*F+f] * x[b,f,m0+ml]
    if (tid < MR) {   // 128 threads, coalesced x loads over m
        const float* xb = x + (size_t)b * F * N + m0 + tid;
        float xv[F];
#pragma unroll
        for (int f = 0; f < F; ++f) xv[f] = xb[(size_t)f * N];
#pragma unroll
        for (int c = 0; c < C; ++c) {
#pragma unroll
            for (int j = 0; j < J; ++j) {
                float s = 0.f;
#pragma unroll
                for (int f = 0; f < F; ++f) s += s_cw[c * (J * F) + j * F + f] * xv[f];
                tl[tid * 8 + c * 4 + j] = s;
            }
        }
    }
    __syncthreads();

    // main stream: W rows m0..m0+MR-1, n-range [n0, n0+HN)
    const fx4* Wp = (const fx4*)W + ((size_t)b * N + m0) * N + n0;  // one fx4 == one n

    float acc0 = 0.f, acc1 = 0.f;
#pragma unroll 4
    for (int r = 0; r < MR; ++r) {
        const float4 t0 = *(const float4*)&tl[r * 8];      // uniform LDS broadcast
        const float4 t1 = *(const float4*)&tl[r * 8 + 4];
        fx4 w4 = __builtin_nontemporal_load(Wp + (size_t)r * N + tid);  // wave: 1 KB contiguous
        acc0 += w4.x * t0.x + w4.y * t0.y + w4.z * t0.z + w4.w * t0.w;
        acc1 += w4.x * t1.x + w4.y * t1.y + w4.z * t1.z + w4.w * t1.w;
    }

    // bias once per output, from the mc==0 block
    if (mc == 0) { acc0 += cb[0]; acc1 += cb[1]; }

    // accumulate into out (L2/L3-resident, fence-free device-scope atomics)
    float* o = out + (size_t)(b * N + n0 + tid) * C;
    atomicAdd(o,     acc0);
    atomicAdd(o + 1, acc1);
}

extern "C" void kernel_launch(void* const* d_in, const int* in_sizes, int n_in,
                              void* d_out, int out_size, void* d_ws, size_t ws_size,
                              hipStream_t stream) {
    const float* W  = (const float*)d_in[0];
    const float* x  = (const float*)d_in[1];
    const float* cw = (const float*)d_in[2];
    const float* cb = (const float*)d_in[3];
    float* out  = (float*)d_out;

    hipMemsetAsync(out, 0, (size_t)out_size * sizeof(float), stream);  // 128 KB, graph-safe
    gnn_main_kernel<<<dim3(GRID), dim3(512), 0, stream>>>(W, x, cw, cb, out);
}